// Round 1
// baseline (249.781 us; speedup 1.0000x reference)
//
#include <hip/hip_runtime.h>

#define NTOK 32768

typedef __attribute__((ext_vector_type(8))) short  bf16x8;
typedef __attribute__((ext_vector_type(8))) unsigned short u16x8;
typedef __attribute__((ext_vector_type(4))) float  f32x4;

__device__ __forceinline__ unsigned short f32_to_bf16(float f) {
    unsigned int u = __float_as_uint(f);
    u += 0x7FFFu + ((u >> 16) & 1u);          // round-to-nearest-even
    return (unsigned short)(u >> 16);
}
__device__ __forceinline__ float bf16_to_f32(unsigned short h) {
    return __uint_as_float(((unsigned int)h) << 16);
}

// ---------------------------------------------------------------------------
// B-stationary MFMA GEMM: C[M,NTOK] = A[M,256] * B[256,NTOK].
// One block per 128-col strip (x) per batch (y): B tile [256k][128n] is
// fetched from HBM EXACTLY ONCE, converted to bf16, stored transposed in LDS
// (Bs[n][k], 16B-granule XOR swizzle -> uniform banks on both write & read).
// Then loop over MCHUNKS m-chunks of 128 rows; A fragments are gathered
// directly from global (16 rows x 64B dense lines per inst; A is tiny and
// L2-resident), so the K-loop has no barriers at all.
// Waves 2x2: each wave = 64 rows x 64 cols = 4 mt x 4 nt MFMA tiles.
// QSOFT: m-chunks 0,1 are q rows -> softmax over each head's 32 rows
// in-register (mt-pair + quad reduction via shfl_xor 16/32) before store.
// ---------------------------------------------------------------------------
template <typename BT, typename CT, int MCHUNKS, bool QSOFT>
__global__ __launch_bounds__(256) void gemm_bstat(
    const unsigned short* __restrict__ A, const BT* __restrict__ B,
    CT* __restrict__ C, long sA, long sB, long sC)
{
    const int bz = blockIdx.y;
    A += (long)bz * sA; B += (long)bz * sB; C += (long)bz * sC;
    const int col0 = blockIdx.x * 128;

    __shared__ unsigned short Bs[128 * 256];   // 64 KB

    const int t = threadIdx.x;
    const int wave = t >> 6, lane = t & 63;
    const int wm = wave >> 1, wn = wave & 1;
    const int m16 = lane & 15, quad = lane >> 4;

    // ---- stage B tile once: [256k][128n] fp32/bf16 -> Bs[n][256k] bf16
    {
        const int n = t & 127;                  // waves 0,1 -> n 0..127, k-half 0
        const int kg0 = (t >> 7) * 16;          // waves 2,3 -> k-half 1
        const int key = n & 7;
        const BT* bcol = B + col0 + n;
        #pragma unroll
        for (int g = 0; g < 16; ++g) {
            const int kg = kg0 + g;             // 16B granule index along k (0..31)
            unsigned short tmp[8];
            #pragma unroll
            for (int i = 0; i < 8; ++i) {
                BT v = bcol[(size_t)(kg * 8 + i) * NTOK];
                if constexpr (sizeof(BT) == 4) tmp[i] = f32_to_bf16((float)v);
                else                           tmp[i] = (unsigned short)v;
            }
            *(u16x8*)&Bs[n * 256 + ((kg ^ key) * 8)] = *(const u16x8*)tmp;
        }
    }
    __syncthreads();   // the only barrier

    const int swk = m16 & 7;

    for (int mc = 0; mc < MCHUNKS; ++mc) {
        const int m0 = mc * 128;
        f32x4 acc[4][4] = {};

        // lane-base pointer into A for this chunk's fragments
        const unsigned short* Abase = A + (size_t)(m0 + wm * 64 + m16) * 256 + quad * 8;

        #pragma unroll
        for (int kk = 0; kk < 8; ++kk) {
            bf16x8 bf[4];
            #pragma unroll
            for (int nt = 0; nt < 4; ++nt) {
                const int col = wn * 64 + nt * 16 + m16;
                bf[nt] = *(const bf16x8*)&Bs[col * 256 + (((kk * 4 + quad) ^ swk) * 8)];
            }
            #pragma unroll
            for (int mt = 0; mt < 4; ++mt) {
                const bf16x8 af = *(const bf16x8*)&Abase[(size_t)mt * 16 * 256 + kk * 32];
                #pragma unroll
                for (int nt = 0; nt < 4; ++nt)
                    acc[mt][nt] = __builtin_amdgcn_mfma_f32_16x16x32_bf16(
                        af, bf[nt], acc[mt][nt], 0, 0, 0);
            }
        }

        // ---- fused q softmax over each head's 32 rows (chunks 0,1 = q rows)
        if (QSOFT && m0 < 256) {
            #pragma unroll
            for (int hj = 0; hj < 2; ++hj) {       // 2 heads per wave (64 rows)
                #pragma unroll
                for (int nt = 0; nt < 4; ++nt) {
                    float mx = -1e30f;
                    #pragma unroll
                    for (int p = 0; p < 2; ++p)
                        #pragma unroll
                        for (int r = 0; r < 4; ++r)
                            mx = fmaxf(mx, acc[hj * 2 + p][nt][r]);
                    mx = fmaxf(mx, __shfl_xor(mx, 16, 64));
                    mx = fmaxf(mx, __shfl_xor(mx, 32, 64));
                    float s = 0.f;
                    #pragma unroll
                    for (int p = 0; p < 2; ++p)
                        #pragma unroll
                        for (int r = 0; r < 4; ++r) {
                            const float e = __expf(acc[hj * 2 + p][nt][r] - mx);
                            acc[hj * 2 + p][nt][r] = e;
                            s += e;
                        }
                    s += __shfl_xor(s, 16, 64);
                    s += __shfl_xor(s, 32, 64);
                    const float inv = 1.0f / s;
                    #pragma unroll
                    for (int p = 0; p < 2; ++p)
                        #pragma unroll
                        for (int r = 0; r < 4; ++r)
                            acc[hj * 2 + p][nt][r] *= inv;
                }
            }
        }

        // ---- store: D[row][col], col = lane&15, row = quad*4 + r
        #pragma unroll
        for (int mt = 0; mt < 4; ++mt) {
            #pragma unroll
            for (int nt = 0; nt < 4; ++nt) {
                #pragma unroll
                for (int r = 0; r < 4; ++r) {
                    const int row = m0 + wm * 64 + mt * 16 + quad * 4 + r;
                    const int col = col0 + wn * 64 + nt * 16 + m16;
                    if constexpr (sizeof(CT) == 4)
                        C[(size_t)row * NTOK + col] = acc[mt][nt][r];
                    else
                        C[(size_t)row * NTOK + col] = f32_to_bf16(acc[mt][nt][r]);
                }
            }
        }
    }
}

// ---------------------------------------------------------------------------
// fp32 -> bf16 cast (vectorized)
// ---------------------------------------------------------------------------
__global__ __launch_bounds__(256) void cast_bf16_kernel(
    const float* __restrict__ src, unsigned short* __restrict__ dst, int n4)
{
    const int i = blockIdx.x * 256 + threadIdx.x;
    if (i < n4) {
        float4 v = ((const float4*)src)[i];
        ushort4 o;
        o.x = f32_to_bf16(v.x); o.y = f32_to_bf16(v.y);
        o.z = f32_to_bf16(v.z); o.w = f32_to_bf16(v.w);
        ((ushort4*)dst)[i] = o;
    }
}

// ---------------------------------------------------------------------------
// MFMA-based context: num[b,h,d,e] = sum_n exp(k[d,n]) * v[e,n];
// den[b,h,d] = sum_n exp(k[d,n]).
// Tokens are the CONTIGUOUS dim of qkv for both k and v, and tokens are the
// MFMA K-dim -> each lane's A/B fragment (row=lane&15, k=quad*8+j) is one
// contiguous 16B global load. No LDS, no barriers, no transposes.
// 8 waves per block = 8 heads; 256 tokens per block; exp() applied
// in-register on the A fragment (rounded to bf16 BEFORE den accumulation so
// num and den use identical weights). Epilogue: fp32 atomicAdd partials.
// ---------------------------------------------------------------------------
#define CCHUNK 256
__global__ __launch_bounds__(512) void ctx_mfma_kernel(
    const unsigned short* __restrict__ qkv,
    float* __restrict__ num, float* __restrict__ den)
{
    const int b = blockIdx.y;
    const int n0 = blockIdx.x * CCHUNK;
    const int h = threadIdx.x >> 6;           // wave id == head id
    const int lane = threadIdx.x & 63;
    const int m16 = lane & 15, quad = lane >> 4;

    const unsigned short* kb =
        qkv + ((long)b * 768 + 256 + h * 32 + m16) * (long)NTOK + n0 + quad * 8;
    const unsigned short* vb =
        qkv + ((long)b * 768 + 512 + h * 32 + m16) * (long)NTOK + n0 + quad * 8;

    f32x4 acc[2][2] = {};       // [dtile][etile]
    float dp[2] = {0.f, 0.f};   // den partials: chan d = dt*16+m16, this quad's toks

    #pragma unroll
    for (int n = 0; n < CCHUNK; n += 32) {
        bf16x8 af[2], bfv[2];
        #pragma unroll
        for (int dt = 0; dt < 2; ++dt) {
            const u16x8 kr = *(const u16x8*)(kb + (size_t)dt * 16 * NTOK + n);
            unsigned short tmp[8];
            #pragma unroll
            for (int i = 0; i < 8; ++i) {
                const float e = __expf(bf16_to_f32(kr[i]));
                const unsigned short eb = f32_to_bf16(e);
                tmp[i] = eb;
                dp[dt] += bf16_to_f32(eb);
            }
            af[dt] = *(const bf16x8*)tmp;
        }
        #pragma unroll
        for (int et = 0; et < 2; ++et)
            bfv[et] = *(const bf16x8*)(vb + (size_t)et * 16 * NTOK + n);
        #pragma unroll
        for (int dt = 0; dt < 2; ++dt)
            #pragma unroll
            for (int et = 0; et < 2; ++et)
                acc[dt][et] = __builtin_amdgcn_mfma_f32_16x16x32_bf16(
                    af[dt], bfv[et], acc[dt][et], 0, 0, 0);
    }

    // num: d = dt*16 + quad*4 + r (C-layout row), e = et*16 + m16 (C-layout col)
    float* nbase = num + ((long)(b * 8 + h) * 32) * 32;
    #pragma unroll
    for (int dt = 0; dt < 2; ++dt)
        #pragma unroll
        for (int et = 0; et < 2; ++et)
            #pragma unroll
            for (int r = 0; r < 4; ++r)
                atomicAdd(&nbase[(dt * 16 + quad * 4 + r) * 32 + et * 16 + m16],
                          acc[dt][et][r]);

    // den: reduce each dtile's partial across the 4 quads
    #pragma unroll
    for (int dt = 0; dt < 2; ++dt) {
        float s = dp[dt];
        s += __shfl_xor(s, 16, 64);
        s += __shfl_xor(s, 32, 64);
        if (quad == 0)
            atomicAdd(&den[b * 256 + h * 32 + dt * 16 + m16], s);
    }
}

// ---------------------------------------------------------------------------
// W2[b][o][h*32+d] = (sum_e w_out[o,h*32+e] * num[b,h,d,e]) / den[b,h*32+d]
// ---------------------------------------------------------------------------
__global__ __launch_bounds__(256) void combine_kernel(
    const float* __restrict__ w_out, const float* __restrict__ num,
    const float* __restrict__ den, unsigned short* __restrict__ W2)
{
    const int tid = blockIdx.x * 256 + threadIdx.x;   // 2*256*256 total
    const int b = tid >> 16;
    const int rem = tid & 65535;
    const int o = rem >> 8;
    const int i = rem & 255;
    const int h = i >> 5, d = i & 31;
    const float* wrow = w_out + o * 256 + h * 32;
    const float* nrow = num + (((long)(b * 8 + h) * 32 + d) << 5);
    float s = 0.f;
    #pragma unroll
    for (int e = 0; e < 32; ++e) s += wrow[e] * nrow[e];
    W2[tid] = f32_to_bf16(s / den[b * 256 + h * 32 + d]);
}

// ---------------------------------------------------------------------------
extern "C" void kernel_launch(void* const* d_in, const int* in_sizes, int n_in,
                              void* d_out, int out_size, void* d_ws, size_t ws_size,
                              hipStream_t stream)
{
    const float* x     = (const float*)d_in[0];   // [2,256,32768]
    const float* w_qkv = (const float*)d_in[1];   // [768,256]
    const float* w_out = (const float*)d_in[2];   // [256,256]
    float* out = (float*)d_out;                   // [2,256,32768]

    // workspace layout
    unsigned short* qkv_bf = (unsigned short*)d_ws;           // 2*768*32768 bf16
    const long qkv_elems = 2L * 768 * NTOK;
    unsigned short* wqkv_bf = qkv_bf + qkv_elems;             // 768*256 bf16
    unsigned short* W2 = wqkv_bf + 768 * 256;                 // 2*256*256 bf16
    float* num  = (float*)(W2 + 2 * 256 * 256);               // 16384
    float* den  = num + 16384;                                // 512

    hipMemsetAsync(num, 0, (16384 + 512) * sizeof(float), stream);

    // 0) cast w_qkv to bf16
    cast_bf16_kernel<<<192, 256, 0, stream>>>(w_qkv, wqkv_bf, 768 * 256 / 4);

    // 1) qkv = w_qkv @ x, q rows softmax'd in-epilogue; B (x) read once
    gemm_bstat<float, unsigned short, 6, true><<<dim3(256, 2), 256, 0, stream>>>(
        wqkv_bf, x, qkv_bf, 0L, 256L * NTOK, 768L * NTOK);

    // 2) context num/den via MFMA, fragments gathered straight from global
    ctx_mfma_kernel<<<dim3(NTOK / CCHUNK, 2), 512, 0, stream>>>(qkv_bf, num, den);

    // 3) W2 = fold(w_out, context) -> bf16
    combine_kernel<<<512, 256, 0, stream>>>(w_out, num, den, W2);

    // 4) out(fp32) = W2(bf16) @ q_soft(bf16); B (q_soft) read once
    gemm_bstat<unsigned short, float, 2, false><<<dim3(256, 2), 256, 0, stream>>>(
        W2, qkv_bf, out, 65536L, 768L * NTOK, 256L * NTOK);
}